// Round 4
// baseline (157.504 us; speedup 1.0000x reference)
//
#include <hip/hip_runtime.h>
#include <stdint.h>

#define RES 64
#define NVOX (RES * RES * RES)
#define NPTS 4194304
#define TPB 256
#define MAIN_BLOCKS 2048   // NPTS / 8 pts-per-thread / 256 threads

// Workspace: [0, NVOX*4) quantized table, 1 uint32 per voxel:
//   bits [0,10)=qx, [10,20)=qy, [20,30)=qz, bit 30 = voxel mask.

__global__ __launch_bounds__(256) void build_table_kernel(
    const float* __restrict__ cp, const int* __restrict__ vox,
    uint32_t* __restrict__ tq)
{
    int i = blockIdx.x * 256 + threadIdx.x;   // grid exactly covers NVOX
    float x = cp[3 * i + 0];
    float y = cp[3 * i + 1];
    float z = cp[3 * i + 2];
    uint32_t qx = (uint32_t)__float2int_rn(fminf(fmaxf(x, 0.f), 1.f) * 1023.0f);
    uint32_t qy = (uint32_t)__float2int_rn(fminf(fmaxf(y, 0.f), 1.f) * 1023.0f);
    uint32_t qz = (uint32_t)__float2int_rn(fminf(fmaxf(z, 0.f), 1.f) * 1023.0f);
    uint32_t m  = (vox[i] != 0) ? (1u << 30) : 0u;
    tq[i] = qx | (qy << 10) | (qz << 20) | m;
}

__device__ __forceinline__ int voxel_index(float x, float y, float z)
{
    // clamp(floor(x*64), 0, 63) via float med3, then pack (ix<<12)|(iy<<6)|iz
    float fx = __builtin_amdgcn_fmed3f(floorf(x * 64.0f), 0.0f, 63.0f);
    float fy = __builtin_amdgcn_fmed3f(floorf(y * 64.0f), 0.0f, 63.0f);
    float fz = __builtin_amdgcn_fmed3f(floorf(z * 64.0f), 0.0f, 63.0f);
    int ix = (int)fx, iy = (int)fy, iz = (int)fz;
    return (ix << 12) | (iy << 6) | iz;
}

__global__ __launch_bounds__(256) void sym_loss_kernel(
    const float4* __restrict__ pts,     // N*3 floats viewed as float4
    const float* __restrict__ planes,   // 3x4
    const float* __restrict__ axes,     // 3x4
    const uint32_t* __restrict__ tq,    // NVOX packed entries
    float* __restrict__ out)
{
    const int tid = threadIdx.x;

    // Per-transform params (broadcast loads).
    float nx[3], ny[3], nz[3], nd[3], nsc[3];
#pragma unroll
    for (int k = 0; k < 3; ++k) {
        float a = planes[4 * k + 0], b = planes[4 * k + 1];
        float c = planes[4 * k + 2], d = planes[4 * k + 3];
        nx[k] = a; ny[k] = b; nz[k] = c; nd[k] = d;
        nsc[k] = 2.0f / (a * a + b * b + c * c);
    }
    float qs[3], qvx[3], qvy[3], qvz[3], q2w[3];
#pragma unroll
    for (int k = 0; k < 3; ++k) {
        float w = axes[4 * k + 0], x = axes[4 * k + 1];
        float y = axes[4 * k + 2], z = axes[4 * k + 3];
        qs[k]  = w * w - (x * x + y * y + z * z);
        qvx[k] = x; qvy[k] = y; qvz[k] = z;
        q2w[k] = 2.0f * w;
    }

    const int gid    = blockIdx.x * TPB + tid;
    const int stride = MAIN_BLOCKS * TPB;     // thread count; 2 quad-groups each

    float acc = 0.0f;
#pragma unroll
    for (int g = 0; g < 2; ++g) {
        int base = gid + g * stride;          // quad-group index
        float4 f0 = pts[3 * base + 0];
        float4 f1 = pts[3 * base + 1];
        float4 f2 = pts[3 * base + 2];
        float px[4] = {f0.x, f0.w, f1.z, f2.y};
        float py[4] = {f0.y, f1.x, f1.w, f2.z};
        float pz[4] = {f0.z, f1.y, f2.x, f2.w};

#pragma unroll
        for (int j = 0; j < 4; ++j) {
            float x = px[j], y = py[j], z = pz[j];
            float tx[6], ty[6], tz[6];

            // 3 reflections
#pragma unroll
            for (int k = 0; k < 3; ++k) {
                float coef = (x * nx[k] + y * ny[k] + z * nz[k] + nd[k]) * nsc[k];
                tx[k] = x - coef * nx[k];
                ty[k] = y - coef * ny[k];
                tz[k] = z - coef * nz[k];
            }
            // 3 rotations: r = (w^2 - v.v)*u + 2(v.u)*v + 2w*(v x u)
#pragma unroll
            for (int k = 0; k < 3; ++k) {
                float dot2 = 2.0f * (qvx[k] * x + qvy[k] * y + qvz[k] * z);
                float cx = qvy[k] * z - qvz[k] * y;
                float cy = qvz[k] * x - qvx[k] * z;
                float cz = qvx[k] * y - qvy[k] * x;
                tx[3 + k] = qs[k] * x + dot2 * qvx[k] + q2w[k] * cx;
                ty[3 + k] = qs[k] * y + dot2 * qvy[k] + q2w[k] * cy;
                tz[3 + k] = qs[k] * z + dot2 * qvz[k] + q2w[k] * cz;
            }

            // Batch: 6 indices, 6 loads in flight, then consume.
            uint32_t e[6];
#pragma unroll
            for (int t = 0; t < 6; ++t)
                e[t] = tq[voxel_index(tx[t], ty[t], tz[t])];

#pragma unroll
            for (int t = 0; t < 6; ++t) {
                uint32_t w = e[t];
                float cx = (float)(w & 1023u)         * (1.0f / 1023.0f);
                float cy = (float)((w >> 10) & 1023u) * (1.0f / 1023.0f);
                float cz = (float)((w >> 20) & 1023u) * (1.0f / 1023.0f);
                float dx = tx[t] - cx, dy = ty[t] - cy, dz = tz[t] - cz;
                float d2 = dx * dx + dy * dy + dz * dz;
                float m  = (float)(w >> 30);          // 0.0 or 1.0
                acc += sqrtf(d2) * m;
            }
        }
    }

    // Reduce: wave64 shfl -> LDS -> one atomic per block.
#pragma unroll
    for (int off = 32; off > 0; off >>= 1)
        acc += __shfl_down(acc, off, 64);

    __shared__ float sacc[4];
    int lane = tid & 63;
    int wid  = tid >> 6;
    if (lane == 0) sacc[wid] = acc;
    __syncthreads();
    if (tid == 0) {
        float s = sacc[0] + sacc[1] + sacc[2] + sacc[3];
        atomicAdd(out, s * (1.0f / (float)NPTS));
    }
}

extern "C" void kernel_launch(void* const* d_in, const int* in_sizes, int n_in,
                              void* d_out, int out_size, void* d_ws, size_t ws_size,
                              hipStream_t stream)
{
    const float* sample_points = (const float*)d_in[0];
    const float* closest       = (const float*)d_in[1];
    const int*   voxels        = (const int*)d_in[2];
    const float* planes        = (const float*)d_in[3];
    const float* axes          = (const float*)d_in[4];
    float*       out           = (float*)d_out;

    uint32_t* tq = (uint32_t*)d_ws;   // 1 MB

    (void)hipMemsetAsync(out, 0, sizeof(float), stream);
    build_table_kernel<<<NVOX / 256, 256, 0, stream>>>(closest, voxels, tq);
    sym_loss_kernel<<<MAIN_BLOCKS, TPB, 0, stream>>>(
        (const float4*)sample_points, planes, axes, tq, out);
}

// Round 5
// 131.465 us; speedup vs baseline: 1.1981x; 1.1981x over previous
//
#include <hip/hip_runtime.h>
#include <stdint.h>

#define RES 64
#define NVOX (RES * RES * RES)
#define NPTS 4194304
#define TPB 512
#define MAIN_BLOCKS (NPTS / 8 / TPB)   // 1024 blocks, 8 pts/thread

// Workspace layout:
//   [0, NVOX*4)               : quantized table, 1 uint32/voxel (10/10/10 xyz, bit30 = mask)
//   [NVOX*4, NVOX*4 + NVOX/8) : voxel mask bitfield (32 KB)

__global__ __launch_bounds__(256) void build_table_kernel(
    const float* __restrict__ cp, const int* __restrict__ vox,
    uint32_t* __restrict__ tq, unsigned long long* __restrict__ mbits)
{
    int i = blockIdx.x * 256 + threadIdx.x;   // grid exactly covers NVOX
    float x = cp[3 * i + 0];
    float y = cp[3 * i + 1];
    float z = cp[3 * i + 2];
    uint32_t qx = (uint32_t)__float2int_rn(fminf(fmaxf(x, 0.f), 1.f) * 1023.0f);
    uint32_t qy = (uint32_t)__float2int_rn(fminf(fmaxf(y, 0.f), 1.f) * 1023.0f);
    uint32_t qz = (uint32_t)__float2int_rn(fminf(fmaxf(z, 0.f), 1.f) * 1023.0f);
    uint32_t m  = (vox[i] != 0) ? (1u << 30) : 0u;
    tq[i] = qx | (qy << 10) | (qz << 20) | m;

    unsigned long long b = __ballot(vox[i] != 0);
    if ((threadIdx.x & 63) == 0) mbits[i >> 6] = b;
}

__device__ __forceinline__ int voxel_index(float x, float y, float z)
{
    float fx = __builtin_amdgcn_fmed3f(floorf(x * 64.0f), 0.0f, 63.0f);
    float fy = __builtin_amdgcn_fmed3f(floorf(y * 64.0f), 0.0f, 63.0f);
    float fz = __builtin_amdgcn_fmed3f(floorf(z * 64.0f), 0.0f, 63.0f);
    int ix = (int)fx, iy = (int)fy, iz = (int)fz;
    return (ix << 12) | (iy << 6) | iz;
}

__global__ __launch_bounds__(TPB, 8) void sym_loss_kernel(
    const float4* __restrict__ pts,     // N*3 floats viewed as float4
    const float* __restrict__ planes,   // 3x4
    const float* __restrict__ axes,     // 3x4
    const uint32_t* __restrict__ tq,    // NVOX packed entries
    const uint32_t* __restrict__ mbits, // NVOX bits (8192 dwords)
    float* __restrict__ out)
{
    __shared__ uint32_t smask[NVOX / 32];   // 32 KB
    __shared__ float sacc[TPB / 64];

    const int tid = threadIdx.x;
#pragma unroll
    for (int i = 0; i < NVOX / 32 / TPB; ++i)
        smask[i * TPB + tid] = mbits[i * TPB + tid];

    // Per-transform params (broadcast loads).
    float nx[3], ny[3], nz[3], nd[3], nsc[3];
#pragma unroll
    for (int k = 0; k < 3; ++k) {
        float a = planes[4 * k + 0], b = planes[4 * k + 1];
        float c = planes[4 * k + 2], d = planes[4 * k + 3];
        nx[k] = a; ny[k] = b; nz[k] = c; nd[k] = d;
        nsc[k] = 2.0f / (a * a + b * b + c * c);
    }
    float qs[3], qvx[3], qvy[3], qvz[3], q2w[3];
#pragma unroll
    for (int k = 0; k < 3; ++k) {
        float w = axes[4 * k + 0], x = axes[4 * k + 1];
        float y = axes[4 * k + 2], z = axes[4 * k + 3];
        qs[k]  = w * w - (x * x + y * y + z * z);
        qvx[k] = x; qvy[k] = y; qvz[k] = z;
        q2w[k] = 2.0f * w;
    }

    __syncthreads();

    const int gid    = blockIdx.x * TPB + tid;
    const int stride = MAIN_BLOCKS * TPB;     // total threads; 2 quad-groups each

    float acc = 0.0f;
#pragma unroll
    for (int g = 0; g < 2; ++g) {
        int base = gid + g * stride;          // quad-group index
        float4 f0 = pts[3 * base + 0];
        float4 f1 = pts[3 * base + 1];
        float4 f2 = pts[3 * base + 2];
        float px[4] = {f0.x, f0.w, f1.z, f2.y};
        float py[4] = {f0.y, f1.x, f1.w, f2.z};
        float pz[4] = {f0.z, f1.y, f2.x, f2.w};

#pragma unroll
        for (int j = 0; j < 4; ++j) {
            float x = px[j], y = py[j], z = pz[j];
            float tx[6], ty[6], tz[6];

            // 3 reflections
#pragma unroll
            for (int k = 0; k < 3; ++k) {
                float coef = (x * nx[k] + y * ny[k] + z * nz[k] + nd[k]) * nsc[k];
                tx[k] = x - coef * nx[k];
                ty[k] = y - coef * ny[k];
                tz[k] = z - coef * nz[k];
            }
            // 3 rotations: r = (w^2 - v.v)*u + 2(v.u)*v + 2w*(v x u)
#pragma unroll
            for (int k = 0; k < 3; ++k) {
                float dot2 = 2.0f * (qvx[k] * x + qvy[k] * y + qvz[k] * z);
                float cx = qvy[k] * z - qvz[k] * y;
                float cy = qvz[k] * x - qvx[k] * z;
                float cz = qvx[k] * y - qvy[k] * x;
                tx[3 + k] = qs[k] * x + dot2 * qvx[k] + q2w[k] * cx;
                ty[3 + k] = qs[k] * y + dot2 * qvy[k] + q2w[k] * cy;
                tz[3 + k] = qs[k] * z + dot2 * qvz[k] + q2w[k] * cz;
            }

            // Branchless gated gathers: masked-off lanes all read entry 0
            // (one coalesced line in TA), result multiplied by the mask.
            uint32_t e[6];
            float    mm[6];
#pragma unroll
            for (int t = 0; t < 6; ++t) {
                int idx = voxel_index(tx[t], ty[t], tz[t]);
                uint32_t bit = (smask[idx >> 5] >> (idx & 31)) & 1u;
                mm[t] = (float)bit;
                e[t]  = tq[bit ? idx : 0];
            }

#pragma unroll
            for (int t = 0; t < 6; ++t) {
                uint32_t w = e[t];
                float cx = (float)(w & 1023u)         * (1.0f / 1023.0f);
                float cy = (float)((w >> 10) & 1023u) * (1.0f / 1023.0f);
                float cz = (float)((w >> 20) & 1023u) * (1.0f / 1023.0f);
                float dx = tx[t] - cx, dy = ty[t] - cy, dz = tz[t] - cz;
                acc += sqrtf(dx * dx + dy * dy + dz * dz) * mm[t];
            }
        }
    }

    // Reduce: wave64 shfl -> LDS -> one atomic per block.
#pragma unroll
    for (int off = 32; off > 0; off >>= 1)
        acc += __shfl_down(acc, off, 64);

    int lane = tid & 63;
    int wid  = tid >> 6;
    if (lane == 0) sacc[wid] = acc;
    __syncthreads();
    if (tid == 0) {
        float s = 0.0f;
#pragma unroll
        for (int wv = 0; wv < TPB / 64; ++wv) s += sacc[wv];
        atomicAdd(out, s * (1.0f / (float)NPTS));
    }
}

extern "C" void kernel_launch(void* const* d_in, const int* in_sizes, int n_in,
                              void* d_out, int out_size, void* d_ws, size_t ws_size,
                              hipStream_t stream)
{
    const float* sample_points = (const float*)d_in[0];
    const float* closest       = (const float*)d_in[1];
    const int*   voxels        = (const int*)d_in[2];
    const float* planes        = (const float*)d_in[3];
    const float* axes          = (const float*)d_in[4];
    float*       out           = (float*)d_out;

    uint32_t*           tq    = (uint32_t*)d_ws;                            // 1 MB
    unsigned long long* mbits = (unsigned long long*)((char*)d_ws + NVOX * 4);  // 32 KB

    (void)hipMemsetAsync(out, 0, sizeof(float), stream);
    build_table_kernel<<<NVOX / 256, 256, 0, stream>>>(closest, voxels, tq, mbits);
    sym_loss_kernel<<<MAIN_BLOCKS, TPB, 0, stream>>>(
        (const float4*)sample_points, planes, axes, tq,
        (const uint32_t*)mbits, out);
}